// Round 9
// baseline (45.013 us; speedup 1.0000x reference)
//
#include <hip/hip_runtime.h>
#include <hip/hip_bf16.h>

// CosSim2D (K=3, same-pad, C=32 -> F=32) on MI355X.
// Round 9: BARRIER-FREE main. All prior variants (occupancy/coalescing/
// pipelining/NT/LDS-B) sit at 33-43us with every pipe <25% busy -> the
// invariant is __syncthreads convoying: all waves of a block alternate
// between all-stage (VALU idle) and all-compute (memory idle) in lockstep.
// Fix: each wave stages its OWN 4 halo rows into its OWN LDS region and
// computes its own 2 output rows. Zero barriers; only per-wave lgkmcnt.
// 12 independent waves/CU overlap memory and compute statistically.

#define H_ 224
#define W_ 224
#define C_ 32
#define F_ 32

#define NSTEP 18   // K = 288 = 18 * 16
#define WROWS 4    // staged rows per wave (2 output + 2 halo)
#define HCOLS 34   // staged cols (32 + 2)
#define WSLOTS (WROWS * HCOLS * 8)  // 1088 float4 slots per wave
#define WITER (WSLOTS / 64)         // 17 per lane

typedef __bf16 bf16_t;
typedef bf16_t bf16x8 __attribute__((ext_vector_type(8)));
typedef float f32x16 __attribute__((ext_vector_type(16)));

#define WFRAG_BYTES (NSTEP * 64 * 8 * 2)  // 18432 B

// ---------------- prep (6 blocks): w-norm + exponents + B-fragments ---------
__global__ __launch_bounds__(256) void cos2d_prep(
    const float* __restrict__ w, const float* __restrict__ p,
    const float* __restrict__ q, bf16_t* __restrict__ wfrag,
    float* __restrict__ winv, float* __restrict__ ef) {
  const int tid = threadIdx.x;
  if (blockIdx.x == 0) {
    __shared__ float part[8][32];
    const int f = tid & 31, kg = tid >> 5;
    float s = 0.f;
#pragma unroll
    for (int i = 0; i < 36; ++i) {
      const float v = w[(kg + 8 * i) * F_ + f];
      s += v * v;
    }
    part[kg][f] = s;
    __syncthreads();
    if (tid < 32) {
      float t = 0.f;
#pragma unroll
      for (int g = 0; g < 8; ++g) t += part[g][tid];
      const float qt = q[0] * q[0] * 0.1f;
      winv[tid] = 1.f / (sqrtf(fmaxf(t, 1e-12f)) + qt);
      ef[tid] = p[tid] * p[tid] * 0.01f;
    }
  } else {
    // B-fragment layout for mfma_f32_32x32x16_bf16:
    //   lane l holds col f = l&31, k = s2*16 + (l>>5)*8 + e  (e = 0..7).
    const int t = (blockIdx.x - 1) * 256 + tid;
    if (t < NSTEP * 64) {
      const int s2 = t >> 6, l = t & 63;
      const int ff = l & 31;
      union { bf16_t v[8]; uint4 u; } tv;
#pragma unroll
      for (int e = 0; e < 8; ++e) {
        const int kk = s2 * 16 + ((l >> 5) << 3) + e;
        tv.v[e] = (bf16_t)w[kk * F_ + ff];
      }
      *(uint4*)(wfrag + (size_t)t * 8) = tv.u;
    }
  }
}

// ---------------- main (barrier-free) ---------------------------------------
__global__ __launch_bounds__(256, 3) void cos2d_main(
    const float* __restrict__ img, const bf16_t* __restrict__ wfrag,
    const float* __restrict__ winv, const float* __restrict__ ef,
    const float* __restrict__ q, float* __restrict__ out) {
  // Per-wave private regions; no cross-wave sharing -> no __syncthreads.
  // pixel stride 40 bf16 = 80 B (16B-aligned, 20-bank stride).
  __shared__ bf16_t xt[4][WROWS][HCOLS][40];  // 43520 B
  __shared__ float ssum[4][WROWS][HCOLS];     //  2176 B

  const int tid = threadIdx.x;
  const int lane = tid & 63;
  const int wv = tid >> 6;
  const int lp = lane & 31;

  const int bid = blockIdx.x;
  const int tw = bid % 7;
  const int th = (bid / 7) % 28;
  const int b  = bid / 196;
  const int h0 = th * 8 + wv * 2;   // this wave's first output row
  const int w0 = tw * 32;

  const float qt = q[0] * q[0] * 0.1f;
  const float efv = ef[lp];     // per-filter exponent (filter = lp)
  const float wnv = winv[lp];   // per-filter 1/(||w||+qt)
  // p^2/100 == 1 for this init; guarded so arbitrary inputs stay correct.
  const bool allfast = __all(__builtin_fabsf(efv - 1.0f) < 1e-6f);

  // ---- per-wave staging: rows h0-1..h0+2, cols w0-1..w0+32.
  // 8 lanes per pixel (lane sub reads float4 #sub) -> coalesced 1KB groups.
  // 8-lane shfl reduce gives per-pixel channel sum-of-squares.
#pragma unroll
  for (int i = 0; i < WITER; ++i) {
    const int idx = lane + 64 * i;          // 0..1087
    const int pp = idx >> 3, sub = idx & 7; // 8-lane groups share pp
    const int rr = pp / HCOLS, cc = pp - rr * HCOLS;
    const int hh = h0 - 1 + rr, wc = w0 - 1 + cc;
    float4 v = make_float4(0.f, 0.f, 0.f, 0.f);
    if ((unsigned)hh < H_ && (unsigned)wc < W_)
      v = *(const float4*)(img + ((size_t)(b * H_ + hh) * W_ + wc) * C_ + sub * 4);
    float s = v.x * v.x + v.y * v.y + v.z * v.z + v.w * v.w;
    s += __shfl_xor(s, 1);
    s += __shfl_xor(s, 2);
    s += __shfl_xor(s, 4);
    union { bf16_t h[4]; uint2 u; } pk;
    pk.h[0] = (bf16_t)v.x; pk.h[1] = (bf16_t)v.y;
    pk.h[2] = (bf16_t)v.z; pk.h[3] = (bf16_t)v.w;
    *(uint2*)&xt[wv][rr][cc][sub * 4] = pk.u;
    if (sub == 0) ssum[wv][rr][cc] = s;
  }
  // (compiler inserts lgkmcnt for same-wave LDS dependencies; no barrier)

  // x_norm: 3x3 window sum of per-pixel channel sum-of-squares (fp32 exact)
  float xinv[2];
#pragma unroll
  for (int t = 0; t < 2; ++t) {
    const float xn2 =
        ssum[wv][t + 0][lp] + ssum[wv][t + 0][lp + 1] + ssum[wv][t + 0][lp + 2] +
        ssum[wv][t + 1][lp] + ssum[wv][t + 1][lp + 1] + ssum[wv][t + 1][lp + 2] +
        ssum[wv][t + 2][lp] + ssum[wv][t + 2][lp + 1] + ssum[wv][t + 2][lp + 2];
    xinv[t] = 1.f / (sqrtf(fmaxf(xn2, 1e-12f)) + qt);
  }

  f32x16 acc0, acc1;
#pragma unroll
  for (int i = 0; i < 16; ++i) { acc0[i] = 0.f; acc1[i] = 0.f; }

  // K loop: A lane l -> pixel col = l&31, k = (l>>5)*8+e (8 contig channels
  // from own LDS region); B streamed from wfrag (L1-resident 18 KB).
  const bf16x8* wf4 = (const bf16x8*)wfrag;
#pragma unroll
  for (int s2 = 0; s2 < NSTEP; ++s2) {
    const bf16x8 bf = wf4[s2 * 64 + lane];
    const int pos = s2 >> 1;
    const int dy = pos / 3, dx = pos - dy * 3;
    const int chof = (s2 & 1) * 16 + ((lane >> 5) << 3);
    const bf16x8 a0 = *(const bf16x8*)&xt[wv][0 + dy][lp + dx][chof];
    const bf16x8 a1 = *(const bf16x8*)&xt[wv][1 + dy][lp + dx][chof];
    acc0 = __builtin_amdgcn_mfma_f32_32x32x16_bf16(a0, bf, acc0, 0, 0, 0);
    acc1 = __builtin_amdgcn_mfma_f32_32x32x16_bf16(a1, bf, acc1, 0, 0, 0);
  }

  // epilogue: C/D col = lane&31 (filter), row = (j&3)+8*(j>>2)+4*(lane>>5).
  // Stores full-line coalesced; nontemporal -> don't dirty L2.
#pragma unroll
  for (int t = 0; t < 2; ++t) {
    const f32x16& acc = t ? acc1 : acc0;
    const int obase = (b * H_ + h0 + t) * W_ + w0;
    if (allfast) {
#pragma unroll
      for (int jj = 0; jj < 16; ++jj) {
        const int row = (jj & 3) + 8 * (jj >> 2) + 4 * (lane >> 5);
        const float xi = __shfl(xinv[t], row);
        const float sim = acc[jj] * xi * wnv;
        const float r = copysignf(fabsf(sim) + 1e-12f, sim);  // |x|^1 path
        __builtin_nontemporal_store(r, &out[(size_t)(obase + row) * F_ + lp]);
      }
    } else {
#pragma unroll
      for (int jj = 0; jj < 16; ++jj) {
        const int row = (jj & 3) + 8 * (jj >> 2) + 4 * (lane >> 5);
        const float xi = __shfl(xinv[t], row);
        const float sim = acc[jj] * xi * wnv;
        const float ps = fabsf(sim) + 1e-12f;
        float r = exp2f(efv * __log2f(ps));
        r = copysignf(r, sim);
        __builtin_nontemporal_store(r, &out[(size_t)(obase + row) * F_ + lp]);
      }
    }
  }
}

// ---------------- launch ----------------------------------------------------
extern "C" void kernel_launch(void* const* d_in, const int* in_sizes, int n_in,
                              void* d_out, int out_size, void* d_ws, size_t ws_size,
                              hipStream_t stream) {
  const float* img = (const float*)d_in[0];
  const float* w   = (const float*)d_in[1];
  const float* p   = (const float*)d_in[2];
  const float* q   = (const float*)d_in[3];

  bf16_t* wfrag = (bf16_t*)d_ws;
  float*  winv  = (float*)((char*)d_ws + WFRAG_BYTES);
  float*  ef    = winv + 64;

  cos2d_prep<<<6, 256, 0, stream>>>(w, p, q, wfrag, winv, ef);
  // 8 images * 28 row-tiles * 7 col-tiles = 1568 blocks, 256 thr (4 indep waves)
  cos2d_main<<<1568, 256, 0, stream>>>(img, wfrag, winv, ef, q, (float*)d_out);
}

// Round 10
// 32.674 us; speedup vs baseline: 1.3776x; 1.3776x over previous
//
#include <hip/hip_runtime.h>
#include <hip/hip_bf16.h>

// CosSim2D (K=3, same-pad, C=32 -> F=32) on MI355X.
// Round 10: DMA staging via global_load_lds (the guide's #1 missed opt).
//   r6 ablation: staging = 9.5us alone, MLP-capped by the compiler's VGPR
//   round-trip (VGPR_Count 48-68 every round). Fix: fp32 halo tile staged
//   HBM->LDS by global_load_lds (no VGPRs, ~44 loads in flight per wave),
//   XOR-swizzled source addresses (linear LDS dest, swizzled ds_read) so
//   stride-128B fragment reads are conflict-free. bf16 cvt + x-norm sumsq
//   fused into the K-loop (staging does zero VALU work). bfrag preloaded
//   (registers now free).

#define H_ 224
#define W_ 224
#define C_ 32
#define F_ 32

#define NSTEP 18   // K = 288 = 18 * 16
#define HROWS 10   // staged halo rows (8 + 2)
#define HCOLS 34   // staged halo cols (32 + 2)
#define NPIX (HROWS * HCOLS)     // 340 pixels
#define NGRAN (NPIX * 8)         // 2720 16B granules (fp32, 128B/pixel)
#define NGRAN_PAD 2816           // pad so the last DMA iter stays in-bounds

typedef __bf16 bf16_t;
typedef bf16_t bf16x8 __attribute__((ext_vector_type(8)));
typedef float f32x16 __attribute__((ext_vector_type(16)));

#define WFRAG_BYTES (NSTEP * 64 * 8 * 2)  // 18432 B

// HBM/L2 -> LDS direct DMA, 16B per lane. LDS dest: wave-uniform base +
// lane*16 (linear). Global src: per-lane (pre-swizzled by caller).
__device__ __forceinline__ void dma16(const void* gp, void* lp) {
  __builtin_amdgcn_global_load_lds(
      (const __attribute__((address_space(1))) void*)gp,
      (__attribute__((address_space(3))) void*)lp, 16, 0, 0);
}

// ---------------- prep (6 blocks): w-norm + exponents + B-fragments ---------
__global__ __launch_bounds__(256) void cos2d_prep(
    const float* __restrict__ w, const float* __restrict__ p,
    const float* __restrict__ q, bf16_t* __restrict__ wfrag,
    float* __restrict__ winv, float* __restrict__ ef) {
  const int tid = threadIdx.x;
  if (blockIdx.x == 0) {
    __shared__ float part[8][32];
    const int f = tid & 31, kg = tid >> 5;
    float s = 0.f;
#pragma unroll
    for (int i = 0; i < 36; ++i) {
      const float v = w[(kg + 8 * i) * F_ + f];
      s += v * v;
    }
    part[kg][f] = s;
    __syncthreads();
    if (tid < 32) {
      float t = 0.f;
#pragma unroll
      for (int g = 0; g < 8; ++g) t += part[g][tid];
      const float qt = q[0] * q[0] * 0.1f;
      winv[tid] = 1.f / (sqrtf(fmaxf(t, 1e-12f)) + qt);
      ef[tid] = p[tid] * p[tid] * 0.01f;
    }
  } else {
    // B-fragment layout for mfma_f32_32x32x16_bf16:
    //   lane l holds col f = l&31, k = s2*16 + (l>>5)*8 + e  (e = 0..7).
    const int t = (blockIdx.x - 1) * 256 + tid;
    if (t < NSTEP * 64) {
      const int s2 = t >> 6, l = t & 63;
      const int ff = l & 31;
      union { bf16_t v[8]; uint4 u; } tv;
#pragma unroll
      for (int e = 0; e < 8; ++e) {
        const int kk = s2 * 16 + ((l >> 5) << 3) + e;
        tv.v[e] = (bf16_t)w[kk * F_ + ff];
      }
      *(uint4*)(wfrag + (size_t)t * 8) = tv.u;
    }
  }
}

// ---------------- main ------------------------------------------------------
__global__ __launch_bounds__(256, 3) void cos2d_main(
    const float* __restrict__ img, const bf16_t* __restrict__ wfrag,
    const float* __restrict__ winv, const float* __restrict__ ef,
    const float* __restrict__ q, float* __restrict__ out) {
  // fp32 halo tile. Granule g=16B. Pixel p's fp32 chunk c (4 floats) lives at
  // granule p*8 + (c ^ (p&7)) -> 8 consecutive pixels at fixed c cover all 32
  // banks (conflict-free b128 reads at pixel-stride 128B).
  __shared__ __align__(16) float xt[NGRAN_PAD * 4];  // 45056 B -> 3 blk/CU

  const int tid = threadIdx.x;
  const int lane = tid & 63;
  const int wv = tid >> 6;
  const int lp = lane & 31;
  const int hi2 = (lane >> 5) * 2;   // fp32-chunk offset from lane-half

  const int bid = blockIdx.x;
  const int tw = bid % 7;
  const int th = (bid / 7) % 28;
  const int b  = bid / 196;
  const int h0 = th * 8, w0 = tw * 32;

  const float qt = q[0] * q[0] * 0.1f;
  const float efv = ef[lp];     // per-filter exponent (filter = lp)
  const float wnv = winv[lp];   // per-filter 1/(||w||+qt)
  // p^2/100 == 1 for this init; guarded so arbitrary inputs stay correct.
  const bool allfast = __all(__builtin_fabsf(efv - 1.0f) < 1e-6f);

  // ---- preload all 18 B-fragments (regs are free now; loads overlap DMA)
  bf16x8 bfrag[NSTEP];
  const bf16x8* wf4 = (const bf16x8*)wfrag;
#pragma unroll
  for (int s2 = 0; s2 < NSTEP; ++s2) bfrag[s2] = wf4[s2 * 64 + lane];

  // ---- DMA staging: slot s (16B) <- pixel s>>3, chunk (s&7)^((s>>3)&7).
  // Per 8-lane group the swizzled sources permute within ONE 128B line ->
  // coalescing preserved. OOB-of-image slots zero-filled by ds_write.
#pragma unroll
  for (int k = 0; k < 11; ++k) {
    const int s = k * 256 + tid;
    float* lb = &xt[(k * 256 + wv * 64) * 4];  // wave-uniform LDS base
    if (s < NGRAN) {
      const int pp = s >> 3;
      const int c  = (s & 7) ^ (pp & 7);
      const int rr = pp / HCOLS, cc = pp - rr * HCOLS;
      const int hh = h0 - 1 + rr, wc = w0 - 1 + cc;
      if ((unsigned)hh < H_ && (unsigned)wc < W_) {
        dma16(img + ((size_t)(b * H_ + hh) * W_ + wc) * C_ + c * 4, lb);
      } else {
        *(float4*)&xt[(size_t)s * 4] = make_float4(0.f, 0.f, 0.f, 0.f);
      }
    }
  }
  __syncthreads();  // drains vmcnt(0): DMA + bfrag complete

  const int mr0 = wv * 2;  // this wave's 2 output rows (tile-relative)

  f32x16 acc0, acc1;
#pragma unroll
  for (int i = 0; i < 16; ++i) { acc0[i] = 0.f; acc1[i] = 0.f; }
  float psum[4] = {0.f, 0.f, 0.f, 0.f};  // per staged row: lane-half sumsq

  // K-loop over (half h, dx): load 4 row-fragments (rows mr0..mr0+3, shared
  // by both accumulators), fuse sumsq (fp32, pre-cvt), cvt to bf16, 6 MFMA.
#pragma unroll
  for (int h = 0; h < 2; ++h) {
#pragma unroll
    for (int dx = 0; dx < 3; ++dx) {
      const int c0 = h * 4 + hi2;  // fp32 chunk: ch = (h*16 + hi*8)/4
      bf16x8 af[4];
#pragma unroll
      for (int r = 0; r < 4; ++r) {
        const int p = (mr0 + r) * HCOLS + lp + dx;
        const int g0 = p * 8 + ((c0 + 0) ^ (p & 7));
        const int g1 = p * 8 + ((c0 + 1) ^ (p & 7));
        const float4 f0 = *(const float4*)&xt[(size_t)g0 * 4];
        const float4 f1 = *(const float4*)&xt[(size_t)g1 * 4];
        psum[r] += f0.x * f0.x + f0.y * f0.y + f0.z * f0.z + f0.w * f0.w +
                   f1.x * f1.x + f1.y * f1.y + f1.z * f1.z + f1.w * f1.w;
        bf16x8 a;
        a[0] = (bf16_t)f0.x; a[1] = (bf16_t)f0.y;
        a[2] = (bf16_t)f0.z; a[3] = (bf16_t)f0.w;
        a[4] = (bf16_t)f1.x; a[5] = (bf16_t)f1.y;
        a[6] = (bf16_t)f1.z; a[7] = (bf16_t)f1.w;
        af[r] = a;
      }
#pragma unroll
      for (int dy = 0; dy < 3; ++dy) {
        const bf16x8 bf = bfrag[2 * (dy * 3 + dx) + h];
        acc0 = __builtin_amdgcn_mfma_f32_32x32x16_bf16(af[dy],     bf, acc0, 0, 0, 0);
        acc1 = __builtin_amdgcn_mfma_f32_32x32x16_bf16(af[dy + 1], bf, acc1, 0, 0, 0);
      }
    }
  }

  // x-norm from fused sums: lane and lane^32 hold complementary 16 channels.
#pragma unroll
  for (int r = 0; r < 4; ++r) psum[r] += __shfl_xor(psum[r], 32);
  const float xn2_0 = psum[0] + psum[1] + psum[2];
  const float xn2_1 = psum[1] + psum[2] + psum[3];
  float xinv[2];
  xinv[0] = 1.f / (sqrtf(fmaxf(xn2_0, 1e-12f)) + qt);
  xinv[1] = 1.f / (sqrtf(fmaxf(xn2_1, 1e-12f)) + qt);

  // epilogue: C/D col = lane&31 (filter), row = (j&3)+8*(j>>2)+4*(lane>>5).
  // Stores full-line coalesced; nontemporal -> don't dirty L2.
#pragma unroll
  for (int t = 0; t < 2; ++t) {
    const f32x16& acc = t ? acc1 : acc0;
    const int obase = (b * H_ + h0 + mr0 + t) * W_ + w0;
    if (allfast) {
#pragma unroll
      for (int jj = 0; jj < 16; ++jj) {
        const int row = (jj & 3) + 8 * (jj >> 2) + 4 * (lane >> 5);
        const float xi = __shfl(xinv[t], row);
        const float sim = acc[jj] * xi * wnv;
        const float r = copysignf(fabsf(sim) + 1e-12f, sim);  // |x|^1 path
        __builtin_nontemporal_store(r, &out[(size_t)(obase + row) * F_ + lp]);
      }
    } else {
#pragma unroll
      for (int jj = 0; jj < 16; ++jj) {
        const int row = (jj & 3) + 8 * (jj >> 2) + 4 * (lane >> 5);
        const float xi = __shfl(xinv[t], row);
        const float sim = acc[jj] * xi * wnv;
        const float ps = fabsf(sim) + 1e-12f;
        float r = exp2f(efv * __log2f(ps));
        r = copysignf(r, sim);
        __builtin_nontemporal_store(r, &out[(size_t)(obase + row) * F_ + lp]);
      }
    }
  }
}

// ---------------- launch ----------------------------------------------------
extern "C" void kernel_launch(void* const* d_in, const int* in_sizes, int n_in,
                              void* d_out, int out_size, void* d_ws, size_t ws_size,
                              hipStream_t stream) {
  const float* img = (const float*)d_in[0];
  const float* w   = (const float*)d_in[1];
  const float* p   = (const float*)d_in[2];
  const float* q   = (const float*)d_in[3];

  bf16_t* wfrag = (bf16_t*)d_ws;
  float*  winv  = (float*)((char*)d_ws + WFRAG_BYTES);
  float*  ef    = winv + 64;

  cos2d_prep<<<6, 256, 0, stream>>>(w, p, q, wfrag, winv, ef);
  // 8 images * 28 row-tiles * 7 col-tiles = 1568 blocks, 256 threads (4 waves)
  cos2d_main<<<1568, 256, 0, stream>>>(img, wfrag, winv, ef, q, (float*)d_out);
}